// Round 7
// baseline (298.815 us; speedup 1.0000x reference)
//
#include <hip/hip_runtime.h>

#define N_NODES 50000
#define N_EDGES 600000
#define HID 128
#define LN_EPS 1e-5f

typedef __attribute__((ext_vector_type(8))) short short8;
typedef __attribute__((ext_vector_type(4))) float f32x4;

__device__ inline float b2f(unsigned short u) {
    union { unsigned int i; float f; } v;
    v.i = ((unsigned int)u) << 16;
    return v.f;
}
__device__ inline unsigned short f2b(float f) {   // round-to-nearest-even
    union { float f; unsigned int u; } v; v.f = f;
    unsigned int r = (v.u + 0x7FFFu + ((v.u >> 16) & 1u)) >> 16;
    return (unsigned short)r;
}

// ================= CSR build =================

__global__ __launch_bounds__(256) void k_hist(const int* __restrict__ ei, int* __restrict__ counts) {
    int e = blockIdx.x * 256 + threadIdx.x;
    if (e < N_EDGES) atomicAdd(&counts[ei[N_EDGES + e]], 1);
}

// slab-base assignment via per-wave scan + one atomic per wave; fused dinv
__global__ __launch_bounds__(256) void k_slab(const int* __restrict__ counts,
                                              int* __restrict__ gtotal,
                                              int* __restrict__ slab,
                                              float* __restrict__ dinv) {
    const int idx  = blockIdx.x * 256 + threadIdx.x;
    const int lane = threadIdx.x & 63;
    const int c = (idx < N_NODES) ? counts[idx] : 0;

    int incl = c;
#pragma unroll
    for (int off = 1; off < 64; off <<= 1) {
        int n = __shfl_up(incl, off);
        if (lane >= off) incl += n;
    }
    const int wtot = __shfl(incl, 63);
    int base = 0;
    if (lane == 0) base = atomicAdd(gtotal, wtot);
    base = __shfl(base, 0);

    if (idx < N_NODES) {
        slab[idx] = base + incl - c;
        dinv[idx] = rsqrtf((float)c + 1.0f);
    }
}

// place edge sources; consumes slab (afterwards slab[d] == end of row d)
__global__ __launch_bounds__(256) void k_place(const int* __restrict__ ei,
                                               int* __restrict__ slab,
                                               int* __restrict__ esrc) {
    int e = blockIdx.x * 256 + threadIdx.x;
    if (e < N_EDGES) {
        const int d = ei[N_EDGES + e];
        const int pos = atomicAdd(&slab[d], 1);
        esrc[pos] = ei[e];
    }
}

// both weights fp32 -> bf16 transposed, one launch (128 blocks)
__global__ __launch_bounds__(256) void k_wt2(const float* __restrict__ W1, unsigned short* __restrict__ WT1,
                                             const float* __restrict__ W2, unsigned short* __restrict__ WT2) {
    const int i = blockIdx.x * 256 + threadIdx.x;
    if (i < 16384) {
        const int k = i >> 7, n = i & 127;
        WT1[n * 128 + k] = f2b(W1[i]);
    } else {
        const int j = i - 16384;
        const int k = j >> 7, n = j & 127;
        WT2[n * 128 + k] = f2b(W2[j]);
    }
}

// ============ MFMA GEMM: hb[M,128](bf16) = dinv[row] * (A[M,128] @ WT^T) ============
__device__ inline short8 load_a_frag(const unsigned short* p) {
    return *(const short8*)p;
}
__device__ inline short8 load_a_frag(const float* p) {
    const float4 v0 = *(const float4*)p;
    const float4 v1 = *(const float4*)(p + 4);
    short8 r;
    r[0] = (short)f2b(v0.x); r[1] = (short)f2b(v0.y);
    r[2] = (short)f2b(v0.z); r[3] = (short)f2b(v0.w);
    r[4] = (short)f2b(v1.x); r[5] = (short)f2b(v1.y);
    r[6] = (short)f2b(v1.z); r[7] = (short)f2b(v1.w);
    return r;
}

template <typename TA>
__global__ __launch_bounds__(256) void k_gemm(const TA* __restrict__ A,
                                              const unsigned short* __restrict__ WT,
                                              const float* __restrict__ dinv,
                                              unsigned short* __restrict__ hb, int M) {
    const int tid  = threadIdx.x;
    const int lane = tid & 63;
    const int ln   = lane & 15;
    const int quad = lane >> 4;
    const int m0   = blockIdx.x * 64 + (tid >> 6) * 16;

    f32x4 acc[8];
#pragma unroll
    for (int t = 0; t < 8; ++t) acc[t] = (f32x4){0.f, 0.f, 0.f, 0.f};

    int arow = m0 + ln;
    if (arow >= M) arow = M - 1;
    const TA* aptr = A + (size_t)arow * HID + quad * 8;
    const unsigned short* bptr = WT + (size_t)ln * HID + quad * 8;

#pragma unroll
    for (int ks = 0; ks < 4; ++ks) {
        const short8 a = load_a_frag(aptr + ks * 32);
#pragma unroll
        for (int t = 0; t < 8; ++t) {
            const short8 b = *(const short8*)(bptr + (size_t)t * 16 * HID + ks * 32);
            acc[t] = __builtin_amdgcn_mfma_f32_16x16x32_bf16(a, b, acc[t], 0, 0, 0);
        }
    }

    // epilogue: scale row by dinv[row], store bf16
    float dv[4];
#pragma unroll
    for (int r = 0; r < 4; ++r) {
        int row = m0 + quad * 4 + r;
        if (row >= M) row = M - 1;
        dv[r] = dinv[row];
    }
#pragma unroll
    for (int t = 0; t < 8; ++t) {
#pragma unroll
        for (int r = 0; r < 4; ++r) {
            const int row = m0 + quad * 4 + r;
            if (row < M) hb[(size_t)row * HID + t * 16 + ln] = f2b(acc[t][r] * dv[r]);
        }
    }
}

// ====== fused CSR gather-aggregate + bias + LayerNorm + ReLU over pre-scaled rows ======
// wave per dst row: 8 edge-groups x 8 feature-lanes; lane owns 16 feats (2x16B gathers)
// y = dinv[row] * (sum_{s in N(row)} hb'[s] + hb'[row]) + b   where hb' = dinv*h
__global__ __launch_bounds__(256) void k_agg_ln(const int* __restrict__ slab_end,
                                                const int* __restrict__ counts,
                                                const int* __restrict__ esrc,
                                                const unsigned short* __restrict__ h,
                                                const float* __restrict__ dinv,
                                                const float* __restrict__ b,
                                                const float* __restrict__ g,
                                                const float* __restrict__ be,
                                                float* __restrict__ outf,          // may be null
                                                unsigned short* __restrict__ outb) // may be null
{
    const int row  = blockIdx.x * 4 + (threadIdx.x >> 6);
    const int lane = threadIdx.x & 63;
    const int grp  = lane >> 3;      // 0..7: edge slot
    const int fl   = lane & 7;       // feature lane: owns feats 16*fl .. 16*fl+15
    if (row >= N_NODES) return;

    const int e1 = slab_end[row];
    const int e0 = e1 - counts[row];
    const size_t fof = 16 * fl;

    float acc[16];
#pragma unroll
    for (int j = 0; j < 16; ++j) acc[j] = 0.f;

    int e = e0 + grp;
    for (; e + 8 < e1; e += 16) {
        const int sA = esrc[e];
        const int sB = esrc[e + 8];
        const unsigned short* pA = h + (size_t)sA * HID + fof;
        const unsigned short* pB = h + (size_t)sB * HID + fof;
        const short8 a0 = *(const short8*)pA;
        const short8 a1 = *(const short8*)(pA + 8);
        const short8 c0 = *(const short8*)pB;
        const short8 c1 = *(const short8*)(pB + 8);
#pragma unroll
        for (int j = 0; j < 8; ++j) {
            acc[j]     += b2f((unsigned short)a0[j]) + b2f((unsigned short)c0[j]);
            acc[8 + j] += b2f((unsigned short)a1[j]) + b2f((unsigned short)c1[j]);
        }
    }
    if (e < e1) {
        const int sA = esrc[e];
        const unsigned short* pA = h + (size_t)sA * HID + fof;
        const short8 a0 = *(const short8*)pA;
        const short8 a1 = *(const short8*)(pA + 8);
#pragma unroll
        for (int j = 0; j < 8; ++j) {
            acc[j]     += b2f((unsigned short)a0[j]);
            acc[8 + j] += b2f((unsigned short)a1[j]);
        }
    }

    // self-term: group 0 only (counted once after merge)
    if (grp == 0) {
        const unsigned short* pR = h + (size_t)row * HID + fof;
        const short8 r0 = *(const short8*)pR;
        const short8 r1 = *(const short8*)(pR + 8);
#pragma unroll
        for (int j = 0; j < 8; ++j) {
            acc[j]     += b2f((unsigned short)r0[j]);
            acc[8 + j] += b2f((unsigned short)r1[j]);
        }
    }

    // butterfly-merge the 8 edge-groups (all lanes end with full sums)
#pragma unroll
    for (int j = 0; j < 16; ++j) {
        acc[j] += __shfl_xor(acc[j], 8);
        acc[j] += __shfl_xor(acc[j], 16);
        acc[j] += __shfl_xor(acc[j], 32);
    }

    const float dd = dinv[row];
    float v[16], s = 0.f, ss = 0.f;
#pragma unroll
    for (int j = 0; j < 16; ++j) {
        v[j] = fmaf(dd, acc[j], b[fof + j]);
        s += v[j];
        ss = fmaf(v[j], v[j], ss);
    }

    // LN stats across the 8 feature lanes
#pragma unroll
    for (int off = 1; off <= 4; off <<= 1) {
        s  += __shfl_xor(s, off);
        ss += __shfl_xor(ss, off);
    }

    const float mu = s * (1.0f / 128.0f);
    const float var = ss * (1.0f / 128.0f) - mu * mu;
    const float rs = rsqrtf(var + LN_EPS);

    if (grp == 0) {
        float o[16];
#pragma unroll
        for (int j = 0; j < 16; ++j)
            o[j] = fmaxf((v[j] - mu) * rs * g[fof + j] + be[fof + j], 0.0f);

        if (outf) {
#pragma unroll
            for (int q = 0; q < 4; ++q) {
                float4 w = {o[4 * q], o[4 * q + 1], o[4 * q + 2], o[4 * q + 3]};
                *(float4*)(outf + (size_t)row * HID + fof + 4 * q) = w;
            }
        }
        if (outb) {
            unsigned short ob[16];
#pragma unroll
            for (int j = 0; j < 16; ++j) ob[j] = f2b(o[j]);
            *(uint4*)(outb + (size_t)row * HID + fof)     = *(const uint4*)&ob[0];
            *(uint4*)(outb + (size_t)row * HID + fof + 8) = *(const uint4*)&ob[8];
        }
    }
}

// ================= launch =================
extern "C" void kernel_launch(void* const* d_in, const int* in_sizes, int n_in,
                              void* d_out, int out_size, void* d_ws, size_t ws_size,
                              hipStream_t stream) {
    (void)in_sizes; (void)n_in; (void)out_size; (void)ws_size;

    const float* x   = (const float*)d_in[0];
    const int*   ei  = (const int*)d_in[1];     // [2,E]: src = ei[e], dst = ei[E+e]
    const float* W1  = (const float*)d_in[2];
    const float* b1  = (const float*)d_in[3];
    const float* g1  = (const float*)d_in[4];
    const float* be1 = (const float*)d_in[5];
    const float* W2  = (const float*)d_in[6];
    const float* b2  = (const float*)d_in[7];
    const float* g2  = (const float*)d_in[8];
    const float* be2 = (const float*)d_in[9];
    float* out = (float*)d_out;

    // workspace layout (dword offsets)
    int* counts = (int*)d_ws;                              // [0, 50000)
    int* gtotal = counts + N_NODES;                        // [50000]
    int* slab   = (int*)d_ws + 50016;                      // [50016, 100016)
    float* dinv = (float*)d_ws + 100016;                   // [100016, 150016)
    int* esrc   = (int*)d_ws + 150016;                     // [150016, 750016)
    unsigned short* WT1 = (unsigned short*)((int*)d_ws + 750016);
    unsigned short* WT2 = (unsigned short*)((int*)d_ws + 758208);
    unsigned short* hb  = (unsigned short*)((int*)d_ws + 766400);  // 3.2M dwords
    unsigned short* yb  = (unsigned short*)((int*)d_ws + 3966400); // 3.2M dwords

    const int nb_edges = (N_EDGES + 255) / 256;
    const int nb_nodes = (N_NODES + 255) / 256;
    const int nb_gemm  = (N_NODES + 63) / 64;
    const int nb_agg   = (N_NODES + 3) / 4;

    // ---- CSR build ----
    hipMemsetAsync(counts, 0, (N_NODES + 1) * sizeof(int), stream);
    k_hist<<<nb_edges, 256, 0, stream>>>(ei, counts);
    k_slab<<<nb_nodes, 256, 0, stream>>>(counts, gtotal, slab, dinv);
    k_place<<<nb_edges, 256, 0, stream>>>(ei, slab, esrc);   // slab[d] -> row end

    // ---- weights ----
    k_wt2<<<128, 256, 0, stream>>>(W1, WT1, W2, WT2);

    // ---- layer 1 (GEMM reads fp32 x directly; output pre-scaled by dinv) ----
    k_gemm<float><<<nb_gemm, 256, 0, stream>>>(x, WT1, dinv, hb, N_NODES);
    k_agg_ln<<<nb_agg, 256, 0, stream>>>(slab, counts, esrc, hb, dinv, b1, g1, be1, nullptr, yb);

    // ---- layer 2 ----
    k_gemm<unsigned short><<<nb_gemm, 256, 0, stream>>>(yb, WT2, dinv, hb, N_NODES);
    k_agg_ln<<<nb_agg, 256, 0, stream>>>(slab, counts, esrc, hb, dinv, b2, g2, be2, out, nullptr);
}

// Round 8
// 273.038 us; speedup vs baseline: 1.0944x; 1.0944x over previous
//
#include <hip/hip_runtime.h>

#define N_NODES 50000
#define N_EDGES 600000
#define HID 128
#define LN_EPS 1e-5f

typedef __attribute__((ext_vector_type(8))) short short8;
typedef __attribute__((ext_vector_type(4))) float f32x4;

__device__ inline float b2f(unsigned short u) {
    union { unsigned int i; float f; } v;
    v.i = ((unsigned int)u) << 16;
    return v.f;
}
__device__ inline unsigned short f2b(float f) {   // round-to-nearest-even
    union { float f; unsigned int u; } v; v.f = f;
    unsigned int r = (v.u + 0x7FFFu + ((v.u >> 16) & 1u)) >> 16;
    return (unsigned short)r;
}

// ================= CSR build pieces (device bodies) =================

__device__ inline void hist_body(int bid, const int* __restrict__ ei, int* __restrict__ counts) {
    int e = bid * 256 + threadIdx.x;
    if (e < N_EDGES) atomicAdd(&counts[ei[N_EDGES + e]], 1);
}

__device__ inline void wt2_body(int bid, const float* __restrict__ W1, unsigned short* __restrict__ WT1,
                                const float* __restrict__ W2, unsigned short* __restrict__ WT2) {
    const int i = bid * 256 + threadIdx.x;
    if (i < 16384) {
        const int k = i >> 7, n = i & 127;
        WT1[n * 128 + k] = f2b(W1[i]);
    } else {
        const int j = i - 16384;
        const int k = j >> 7, n = j & 127;
        WT2[n * 128 + k] = f2b(W2[j]);
    }
}

// fat kernel 1: hist (blocks [0, nbe)) + weight transposes (blocks [nbe, nbe+128))
__global__ __launch_bounds__(256) void k_hist_wt2(const int* __restrict__ ei, int* __restrict__ counts,
                                                  const float* __restrict__ W1, unsigned short* __restrict__ WT1,
                                                  const float* __restrict__ W2, unsigned short* __restrict__ WT2,
                                                  int nbe) {
    const int bid = blockIdx.x;
    if (bid < nbe) hist_body(bid, ei, counts);
    else wt2_body(bid - nbe, W1, WT1, W2, WT2);
}

// slab-base assignment via per-wave scan + one atomic per wave; fused dinv
__global__ __launch_bounds__(256) void k_slab(const int* __restrict__ counts,
                                              int* __restrict__ gtotal,
                                              int* __restrict__ slab,
                                              float* __restrict__ dinv) {
    const int idx  = blockIdx.x * 256 + threadIdx.x;
    const int lane = threadIdx.x & 63;
    const int c = (idx < N_NODES) ? counts[idx] : 0;

    int incl = c;
#pragma unroll
    for (int off = 1; off < 64; off <<= 1) {
        int n = __shfl_up(incl, off);
        if (lane >= off) incl += n;
    }
    const int wtot = __shfl(incl, 63);
    int base = 0;
    if (lane == 0) base = atomicAdd(gtotal, wtot);
    base = __shfl(base, 0);

    if (idx < N_NODES) {
        slab[idx] = base + incl - c;
        dinv[idx] = rsqrtf((float)c + 1.0f);
    }
}

__device__ inline void place_body(int bid, const int* __restrict__ ei,
                                  int* __restrict__ slab, int* __restrict__ esrc) {
    int e = bid * 256 + threadIdx.x;
    if (e < N_EDGES) {
        const int d = ei[N_EDGES + e];
        const int pos = atomicAdd(&slab[d], 1);
        esrc[pos] = ei[e];
    }
}

// ============ MFMA GEMM body: hb[M,128](bf16) = dinv[row] * (A[M,128] @ WT^T) ============
__device__ inline short8 load_a_frag(const unsigned short* p) {
    return *(const short8*)p;
}
__device__ inline short8 load_a_frag(const float* p) {
    const float4 v0 = *(const float4*)p;
    const float4 v1 = *(const float4*)(p + 4);
    short8 r;
    r[0] = (short)f2b(v0.x); r[1] = (short)f2b(v0.y);
    r[2] = (short)f2b(v0.z); r[3] = (short)f2b(v0.w);
    r[4] = (short)f2b(v1.x); r[5] = (short)f2b(v1.y);
    r[6] = (short)f2b(v1.z); r[7] = (short)f2b(v1.w);
    return r;
}

template <typename TA>
__device__ inline void gemm_body(int bid, const TA* __restrict__ A,
                                 const unsigned short* __restrict__ WT,
                                 const float* __restrict__ dinv,
                                 unsigned short* __restrict__ hb, int M) {
    const int tid  = threadIdx.x;
    const int lane = tid & 63;
    const int ln   = lane & 15;
    const int quad = lane >> 4;
    const int m0   = bid * 64 + (tid >> 6) * 16;

    f32x4 acc[8];
#pragma unroll
    for (int t = 0; t < 8; ++t) acc[t] = (f32x4){0.f, 0.f, 0.f, 0.f};

    int arow = m0 + ln;
    if (arow >= M) arow = M - 1;
    const TA* aptr = A + (size_t)arow * HID + quad * 8;
    const unsigned short* bptr = WT + (size_t)ln * HID + quad * 8;

#pragma unroll
    for (int ks = 0; ks < 4; ++ks) {
        const short8 a = load_a_frag(aptr + ks * 32);
#pragma unroll
        for (int t = 0; t < 8; ++t) {
            const short8 b = *(const short8*)(bptr + (size_t)t * 16 * HID + ks * 32);
            acc[t] = __builtin_amdgcn_mfma_f32_16x16x32_bf16(a, b, acc[t], 0, 0, 0);
        }
    }

    float dv[4];
#pragma unroll
    for (int r = 0; r < 4; ++r) {
        int row = m0 + quad * 4 + r;
        if (row >= M) row = M - 1;
        dv[r] = dinv[row];
    }
#pragma unroll
    for (int t = 0; t < 8; ++t) {
#pragma unroll
        for (int r = 0; r < 4; ++r) {
            const int row = m0 + quad * 4 + r;
            if (row < M) hb[(size_t)row * HID + t * 16 + ln] = f2b(acc[t][r] * dv[r]);
        }
    }
}

// fat kernel 2: gemm layer-1 (blocks [0, nbg)) + CSR place (blocks [nbg, nbg+nbe))
__global__ __launch_bounds__(256) void k_gemm1_place(const float* __restrict__ x,
                                                     const unsigned short* __restrict__ WT1,
                                                     const float* __restrict__ dinv,
                                                     unsigned short* __restrict__ hb,
                                                     const int* __restrict__ ei,
                                                     int* __restrict__ slab,
                                                     int* __restrict__ esrc,
                                                     int nbg) {
    const int bid = blockIdx.x;
    if (bid < nbg) gemm_body<float>(bid, x, WT1, dinv, hb, N_NODES);
    else place_body(bid - nbg, ei, slab, esrc);
}

// standalone gemm (layer 2)
template <typename TA>
__global__ __launch_bounds__(256) void k_gemm(const TA* __restrict__ A,
                                              const unsigned short* __restrict__ WT,
                                              const float* __restrict__ dinv,
                                              unsigned short* __restrict__ hb, int M) {
    gemm_body<TA>(blockIdx.x, A, WT, dinv, hb, M);
}

// ====== fused CSR gather-aggregate + bias + LayerNorm + ReLU over pre-scaled rows ======
// R6-proven shape: wave per dst row, 4 edge-groups x 16 feature-lanes, x2 unroll.
// y = dinv[row] * (sum_{s in N(row)} hb'[s] + hb'[row]) + b   where hb' = dinv*(A@W)
__global__ __launch_bounds__(256) void k_agg_ln(const int* __restrict__ slab_end,
                                                const int* __restrict__ counts,
                                                const int* __restrict__ esrc,
                                                const unsigned short* __restrict__ h,
                                                const float* __restrict__ dinv,
                                                const float* __restrict__ b,
                                                const float* __restrict__ g,
                                                const float* __restrict__ be,
                                                float* __restrict__ outf,          // may be null
                                                unsigned short* __restrict__ outb) // may be null
{
    const int row  = blockIdx.x * 4 + (threadIdx.x >> 6);
    const int lane = threadIdx.x & 63;
    const int grp  = lane >> 4;      // 0..3: edge slot
    const int fl   = lane & 15;      // feature lane: owns feats 8*fl .. 8*fl+7
    if (row >= N_NODES) return;

    const int e1 = slab_end[row];
    const int e0 = e1 - counts[row];
    const size_t fof = 8 * fl;

    float acc[8];
#pragma unroll
    for (int j = 0; j < 8; ++j) acc[j] = 0.f;

    int e = e0 + grp;
    for (; e + 4 < e1; e += 8) {
        const int sA = esrc[e];
        const int sB = esrc[e + 4];
        const short8 vA = *(const short8*)(h + (size_t)sA * HID + fof);
        const short8 vB = *(const short8*)(h + (size_t)sB * HID + fof);
#pragma unroll
        for (int j = 0; j < 8; ++j)
            acc[j] += b2f((unsigned short)vA[j]) + b2f((unsigned short)vB[j]);
    }
    if (e < e1) {
        const int sA = esrc[e];
        const short8 vA = *(const short8*)(h + (size_t)sA * HID + fof);
#pragma unroll
        for (int j = 0; j < 8; ++j)
            acc[j] += b2f((unsigned short)vA[j]);
    }

    // self-term: group 0 only (counted once after merge)
    if (grp == 0) {
        const short8 r0 = *(const short8*)(h + (size_t)row * HID + fof);
#pragma unroll
        for (int j = 0; j < 8; ++j)
            acc[j] += b2f((unsigned short)r0[j]);
    }

    // butterfly-merge the 4 edge-groups
#pragma unroll
    for (int j = 0; j < 8; ++j) {
        acc[j] += __shfl_xor(acc[j], 16);
        acc[j] += __shfl_xor(acc[j], 32);
    }

    const float dd = dinv[row];
    const float4 b0 = *(const float4*)(b + fof);
    const float4 b1 = *(const float4*)(b + fof + 4);
    const float bb[8] = {b0.x, b0.y, b0.z, b0.w, b1.x, b1.y, b1.z, b1.w};

    float v[8], s = 0.f, ss = 0.f;
#pragma unroll
    for (int j = 0; j < 8; ++j) {
        v[j] = fmaf(dd, acc[j], bb[j]);
        s += v[j];
        ss = fmaf(v[j], v[j], ss);
    }

    // LN stats across the 16 feature lanes
#pragma unroll
    for (int off = 1; off <= 8; off <<= 1) {
        s  += __shfl_xor(s, off);
        ss += __shfl_xor(ss, off);
    }

    const float mu = s * (1.0f / 128.0f);
    const float var = ss * (1.0f / 128.0f) - mu * mu;
    const float rs = rsqrtf(var + LN_EPS);

    if (grp == 0) {
        const float4 g0 = *(const float4*)(g + fof);
        const float4 g1 = *(const float4*)(g + fof + 4);
        const float4 e0v = *(const float4*)(be + fof);
        const float4 e1v = *(const float4*)(be + fof + 4);
        const float gg[8] = {g0.x, g0.y, g0.z, g0.w, g1.x, g1.y, g1.z, g1.w};
        const float ee[8] = {e0v.x, e0v.y, e0v.z, e0v.w, e1v.x, e1v.y, e1v.z, e1v.w};
        float o[8];
#pragma unroll
        for (int j = 0; j < 8; ++j)
            o[j] = fmaxf((v[j] - mu) * rs * gg[j] + ee[j], 0.0f);

        if (outf) {
            float4 w0 = {o[0], o[1], o[2], o[3]};
            float4 w1 = {o[4], o[5], o[6], o[7]};
            *(float4*)(outf + (size_t)row * HID + fof) = w0;
            *(float4*)(outf + (size_t)row * HID + fof + 4) = w1;
        }
        if (outb) {
            ushort4 w0 = {f2b(o[0]), f2b(o[1]), f2b(o[2]), f2b(o[3])};
            ushort4 w1 = {f2b(o[4]), f2b(o[5]), f2b(o[6]), f2b(o[7])};
            *(ushort4*)(outb + (size_t)row * HID + fof) = w0;
            *(ushort4*)(outb + (size_t)row * HID + fof + 4) = w1;
        }
    }
}

// ================= launch =================
extern "C" void kernel_launch(void* const* d_in, const int* in_sizes, int n_in,
                              void* d_out, int out_size, void* d_ws, size_t ws_size,
                              hipStream_t stream) {
    (void)in_sizes; (void)n_in; (void)out_size; (void)ws_size;

    const float* x   = (const float*)d_in[0];
    const int*   ei  = (const int*)d_in[1];     // [2,E]: src = ei[e], dst = ei[E+e]
    const float* W1  = (const float*)d_in[2];
    const float* b1  = (const float*)d_in[3];
    const float* g1  = (const float*)d_in[4];
    const float* be1 = (const float*)d_in[5];
    const float* W2  = (const float*)d_in[6];
    const float* b2  = (const float*)d_in[7];
    const float* g2  = (const float*)d_in[8];
    const float* be2 = (const float*)d_in[9];
    float* out = (float*)d_out;

    // workspace layout (dword offsets)
    int* counts = (int*)d_ws;                              // [0, 50000)
    int* gtotal = counts + N_NODES;                        // [50000]
    int* slab   = (int*)d_ws + 50016;                      // [50016, 100016)
    float* dinv = (float*)d_ws + 100016;                   // [100016, 150016)
    int* esrc   = (int*)d_ws + 150016;                     // [150016, 750016)
    unsigned short* WT1 = (unsigned short*)((int*)d_ws + 750016);
    unsigned short* WT2 = (unsigned short*)((int*)d_ws + 758208);
    unsigned short* hb  = (unsigned short*)((int*)d_ws + 766400);  // 3.2M dwords
    unsigned short* yb  = (unsigned short*)((int*)d_ws + 3966400); // 3.2M dwords

    const int nb_edges = (N_EDGES + 255) / 256;            // 2344
    const int nb_nodes = (N_NODES + 255) / 256;            // 196
    const int nb_gemm  = (N_NODES + 63) / 64;              // 782
    const int nb_agg   = (N_NODES + 3) / 4;                // 12500

    // memset covers counts + gtotal
    hipMemsetAsync(counts, 0, (N_NODES + 1) * sizeof(int), stream);

    // K1: hist || weight transposes
    k_hist_wt2<<<nb_edges + 128, 256, 0, stream>>>(ei, counts, W1, WT1, W2, WT2, nb_edges);

    // K2: slab bases + dinv
    k_slab<<<nb_nodes, 256, 0, stream>>>(counts, gtotal, slab, dinv);

    // K3: layer-1 GEMM || CSR place   (independent: gemm needs WT1/x/dinv, place needs slab)
    k_gemm1_place<<<nb_gemm + nb_edges, 256, 0, stream>>>(x, WT1, dinv, hb, ei, slab, esrc, nb_gemm);

    // K4: layer-1 aggregate + LN + ReLU -> yb (bf16)
    k_agg_ln<<<nb_agg, 256, 0, stream>>>(slab, counts, esrc, hb, dinv, b1, g1, be1, nullptr, yb);

    // K5: layer-2 GEMM
    k_gemm<unsigned short><<<nb_gemm, 256, 0, stream>>>(yb, WT2, dinv, hb, N_NODES);

    // K6: layer-2 aggregate + LN + ReLU -> out (fp32)
    k_agg_ln<<<nb_agg, 256, 0, stream>>>(slab, counts, esrc, hb, dinv, b2, g2, be2, out, nullptr);
}